// Round 5
// baseline (247.781 us; speedup 1.0000x reference)
//
#include <hip/hip_runtime.h>

#define NB 32
#define NC 128
#define NH 56
#define NW 56
#define HP 58
#define WP 58
#define KK 1152
#define NPOS 3136                         // 56*56
#define XT_BYTES (NB * HP * WP * NC * 2)  // 27,557,888
#define AW_OFF XT_BYTES

typedef __attribute__((ext_vector_type(8))) short s16x8;
typedef __attribute__((ext_vector_type(4))) float f32x4;
typedef unsigned int u32;

__device__ __forceinline__ unsigned short f2bf(float f) {
    union { float f; unsigned int u; } v; v.f = f;
    unsigned int u = v.u + 0x7fffu + ((v.u >> 16) & 1u);
    return (unsigned short)(u >> 16);
}

__device__ __forceinline__ void gld16(const void* g, void* l) {
    __builtin_amdgcn_global_load_lds(
        (const __attribute__((address_space(1))) u32*)g,
        (__attribute__((address_space(3))) u32*)l, 16, 0, 0);
}

// ---- fused prologue (v1, proven) ----
// blocks [0,1792) transpose x; [1792,4096) permute w.
__global__ void k_pro(const float* __restrict__ x, const float* __restrict__ w,
                      unsigned short* __restrict__ xt, unsigned short* __restrict__ aw) {
    int blk = blockIdx.x;
    int tid = threadIdx.x;
    if (blk >= 1792) {
        int idx = (blk - 1792) * 256 + tid;   // 589824 total
        if (idx < 512 * KK) {
            int j = idx & 7, lane = (idx >> 3) & 63, mt = (idx >> 9) & 31, s = idx >> 14;
            int m = mt * 16 + (lane & 15);
            int kg = s * 32 + (lane >> 4) * 8 + j;
            int g = kg >> 7, ic = kg & 127;
            aw[idx] = f2bf(w[(m * 128 + ic) * 9 + g]);
        }
        return;
    }
    __shared__ unsigned short tile[128 * 57];
    int b = blk / NH, y = blk % NH;
    const float* xb = x + (size_t)b * (NC * NPOS) + y * NW;
#pragma unroll
    for (int p = 0; p < 7; ++p) {
        int idx = p * 256 + tid;            // 1792 float4 = 7168 floats
        int c = idx / 14, i = idx - c * 14;
        float4 v = *(const float4*)(xb + c * NPOS + i * 4);
        unsigned short* tp = &tile[c * 57 + i * 4];
        tp[0] = f2bf(v.x); tp[1] = f2bf(v.y); tp[2] = f2bf(v.z); tp[3] = f2bf(v.w);
    }
    __syncthreads();
    unsigned short* xrow = xt + ((size_t)(b * HP + y + 1) * WP + 1) * NC;
#pragma unroll
    for (int p = 0; p < 4; ++p) {
        int idx = p * 256 + tid;            // 896 = 56 x-pos * 16 chunks
        if (idx < 896) {
            int xp = idx >> 4, cgi = idx & 15;
            s16x8 v8;
#pragma unroll
            for (int j = 0; j < 8; ++j)
                v8[j] = (short)tile[(cgi * 8 + j) * 57 + xp];
            *(s16x8*)(xrow + xp * NC + cgi * 8) = v8;
        }
    }
    if (tid < 128) {
        xt[((size_t)(b * HP + y + 1) * WP + 0) * NC + tid] = 0;
        xt[((size_t)(b * HP + y + 1) * WP + 57) * NC + tid] = 0;
    }
    if (y == 0) {
        unsigned short* r0 = xt + (size_t)(b * HP + 0) * WP * NC;
        for (int i = tid; i < WP * NC; i += 256) r0[i] = 0;
    }
    if (y == 55) {
        unsigned short* r57 = xt + (size_t)(b * HP + 57) * WP * NC;
        for (int i = tid; i < WP * NC; i += 256) r57[i] = 0;
    }
}

// ---- main v5: 3-bank A prefetch (2-beat lead), fully specialized stages ----
// Proven 512-thr geometry: M=512, N=112, 9 stages x 4 beats, 28 MFMA/beat.
// Changes vs the 132us baseline, all aimed at the A-load latency chain:
//  * Abank[3] rotation: beat g uses bank g%3, loaded at beat g-2 (272cy lead
//    >= contended L2 latency). All bank indices compile-time via macro unroll.
//  * bissue issued AFTER beat-1's A-issue: gld16s are newer than every bank
//    the per-beat vmcnt waits need, so B-prefetch is never force-drained;
//    its deadline is the stage-end __syncthreads (~2.5 beats later).
//  * s_setprio(1/0) around MFMA clusters.
__global__ void __launch_bounds__(512, 2) k_main(
    const unsigned short* __restrict__ xt, const unsigned short* __restrict__ aw,
    const float* __restrict__ cwr, const float* __restrict__ cwc,
    const float* __restrict__ brow, const float* __restrict__ bcol,
    const float* __restrict__ bch, float* __restrict__ out) {
    __shared__ __align__(16) unsigned char ldsB[2][28672];   // 112 rows x 256B

    const int tid = threadIdx.x;
    const int lane = tid & 63;
    const int wv = tid >> 6;
    const int l15 = lane & 15, quad = lane >> 4;
    const int ph = (wv & 1) * 2;            // per-parity sub-slice rotation
    const int blk = blockIdx.x;
    const int b = blk / 28;
    const int tile0 = (blk - b * 28) * 112;

    const unsigned char* xt_b = (const unsigned char*)xt + (size_t)b * (HP * WP * NC * 2);
    const unsigned char* gA = (const unsigned char*)aw + wv * 1024 + lane * 16;

    // B staging: wave wv (0..6) stages rows wv*16..+15; gld16 #h covers 4 rows
    // (h*4 + lane>>4), phys chunk lane&15, global chunk (lane&15)^(row&15).
    const unsigned char* gB[4];
    if (wv < 7) {
#pragma unroll
        for (int h = 0; h < 4; ++h) {
            int rl = h * 4 + (lane >> 4);
            int row = wv * 16 + rl;
            int pos = tile0 + row;
            int yy = pos / 56, xx = pos - yy * 56;
            int c = (lane & 15) ^ rl;
            gB[h] = xt_b + ((yy + 1) * WP + (xx + 1)) * (NC * 2) + c * 16;
        }
    }

    s16x8 Abank[3][4];         // [g%3][rank]
    f32x4 acc[4][7] = {};      // [rank][ntile]

    auto aload = [&](int s32, s16x8 (&bank)[4]) {
#pragma unroll
        for (int r = 0; r < 4; ++r)
            bank[r] = *(const s16x8*)(gA + s32 * 32768 + r * 8192);
    };
    auto bissue = [&](int st, int buf) {
        if (wv < 7) {
            int dy = (st * 11) >> 5, dx = st - dy * 3;
            int off = ((dy - 1) * WP + (dx - 1)) * (NC * 2);
            unsigned char* L = &ldsB[buf][wv * 4096];
#pragma unroll
            for (int h = 0; h < 4; ++h) gld16(gB[h] + off, L + h * 1024);
        }
    };

// slice id for global beat G (wave-phase-rotated within its stage)
#define SLC(G) ((((G) >> 2) << 2) + ((((G) & 3) + ph) & 3))

// one K32 beat at global beat G (stage G>>2, buffer BUF = (G>>2)&1).
// DOBISS: issue next stage's B gld16 here (placed at beat 1 of each stage).
#define BEAT(G, BUF, DOBISS)                                                  \
    {                                                                         \
        if ((G) <= 33) aload(SLC((G) + 2), Abank[((G) + 2) % 3]);             \
        if (DOBISS) bissue(((G) >> 2) + 1, (BUF) ^ 1);                        \
        const unsigned char* L = &ldsB[BUF][0];                               \
        const int kkw = (((G) & 3) + ph) & 3;                                 \
        s16x8 bf[7];                                                          \
        _Pragma("unroll")                                                     \
        for (int t = 0; t < 7; ++t)                                           \
            bf[t] = *(const s16x8*)(L + (t * 16 + l15) * 256                  \
                                      + (((kkw * 4 + quad) ^ l15) << 4));     \
        __builtin_amdgcn_s_setprio(1);                                        \
        _Pragma("unroll")                                                     \
        for (int r = 0; r < 4; ++r)                                           \
            _Pragma("unroll")                                                 \
            for (int t = 0; t < 7; ++t)                                       \
                acc[r][t] = __builtin_amdgcn_mfma_f32_16x16x32_bf16(          \
                    Abank[(G) % 3][r], bf[t], acc[r][t], 0, 0, 0);            \
        __builtin_amdgcn_s_setprio(0);                                        \
    }

#define STAGE(ST)                                                             \
    BEAT(4 * (ST) + 0, (ST) & 1, 0)                                           \
    BEAT(4 * (ST) + 1, (ST) & 1, ((ST) < 8))                                  \
    BEAT(4 * (ST) + 2, (ST) & 1, 0)                                           \
    BEAT(4 * (ST) + 3, (ST) & 1, 0)

    // prologue: banks for beats 0,1 + first B tile
    aload(SLC(0), Abank[0]);
    aload(SLC(1), Abank[1]);
    bissue(0, 0);
    __syncthreads();

    STAGE(0) __syncthreads();
    STAGE(1) __syncthreads();
    STAGE(2) __syncthreads();
    STAGE(3) __syncthreads();
    STAGE(4) __syncthreads();
    STAGE(5) __syncthreads();
    STAGE(6) __syncthreads();
    STAGE(7) __syncthreads();
    STAGE(8)
#undef STAGE
#undef BEAT
#undef SLC

    // epilogue: inline softmax over rank + combine + biases, fp32 store
#pragma unroll
    for (int t = 0; t < 7; ++t) {
        int pos = tile0 + t * 16 + l15;
        int yy = pos / 56, xx = pos - yy * 56;
        float v0 = cwr[yy]       + cwc[xx];
        float v1 = cwr[56 + yy]  + cwc[56 + xx];
        float v2 = cwr[112 + yy] + cwc[112 + xx];
        float v3 = cwr[168 + yy] + cwc[168 + xx];
        float mx = fmaxf(fmaxf(v0, v1), fmaxf(v2, v3));
        float e0 = __expf(v0 - mx), e1 = __expf(v1 - mx);
        float e2 = __expf(v2 - mx), e3 = __expf(v3 - mx);
        float inv = 1.0f / (e0 + e1 + e2 + e3);
        float c0 = e0 * inv, c1 = e1 * inv, c2 = e2 * inv, c3 = e3 * inv;
        float rb = brow[yy] + bcol[xx];
#pragma unroll
        for (int r = 0; r < 4; ++r) {
            int ch = wv * 16 + quad * 4 + r;
            float v = acc[0][t][r] * c0 + acc[1][t][r] * c1
                    + acc[2][t][r] * c2 + acc[3][t][r] * c3;
            out[((size_t)b * NC + ch) * NPOS + pos] = v + bch[ch] + rb;
        }
    }
}

extern "C" void kernel_launch(void* const* d_in, const int* in_sizes, int n_in,
                              void* d_out, int out_size, void* d_ws, size_t ws_size,
                              hipStream_t stream) {
    const float* x    = (const float*)d_in[0];
    const float* w    = (const float*)d_in[1];
    const float* cwr  = (const float*)d_in[2];
    const float* cwc  = (const float*)d_in[3];
    const float* brow = (const float*)d_in[4];
    const float* bcol = (const float*)d_in[5];
    const float* bch  = (const float*)d_in[6];
    float* out = (float*)d_out;

    unsigned char* ws = (unsigned char*)d_ws;
    unsigned short* xt = (unsigned short*)ws;
    unsigned short* aw = (unsigned short*)(ws + AW_OFF);

    k_pro<<<4096, 256, 0, stream>>>(x, w, xt, aw);   // xpose + wconv fused
    k_main<<<NB * 28, 512, 0, stream>>>(xt, aw, cwr, cwc, brow, bcol, bch, out);
}

// Round 6
// 227.743 us; speedup vs baseline: 1.0880x; 1.0880x over previous
//
#include <hip/hip_runtime.h>

#define NB 32
#define NC 128
#define NH 56
#define NW 56
#define HP 58
#define WP 58
#define KK 1152
#define NPOS 3136                         // 56*56
#define XT_BYTES (NB * HP * WP * NC * 2)  // 27,557,888
#define AW_OFF XT_BYTES

typedef __attribute__((ext_vector_type(8))) short s16x8;
typedef __attribute__((ext_vector_type(4))) float f32x4;
typedef unsigned int u32;

__device__ __forceinline__ unsigned short f2bf(float f) {
    union { float f; unsigned int u; } v; v.f = f;
    unsigned int u = v.u + 0x7fffu + ((v.u >> 16) & 1u);
    return (unsigned short)(u >> 16);
}

__device__ __forceinline__ void gld16(const void* g, void* l) {
    __builtin_amdgcn_global_load_lds(
        (const __attribute__((address_space(1))) u32*)g,
        (__attribute__((address_space(3))) u32*)l, 16, 0, 0);
}

// ---- fused prologue (v1 + row-keyed chunk swizzle) ----
// blocks [0,1792) transpose x; [1792,4096) permute w.
// xt rows now store chunk c at phys position c ^ (rowG & 15), where
// rowG = (y+1)*58 + (x+1) is the padded spatial row index within the batch.
// (XOR involution; k_main reads phys (K ^ (R&15)) from its 16-row-aligned
// slab so local R ≡ global rowG mod 16.)
__global__ void k_pro(const float* __restrict__ x, const float* __restrict__ w,
                      unsigned short* __restrict__ xt, unsigned short* __restrict__ aw) {
    int blk = blockIdx.x;
    int tid = threadIdx.x;
    if (blk >= 1792) {
        int idx = (blk - 1792) * 256 + tid;   // 589824 total
        if (idx < 512 * KK) {
            int j = idx & 7, lane = (idx >> 3) & 63, mt = (idx >> 9) & 31, s = idx >> 14;
            int m = mt * 16 + (lane & 15);
            int kg = s * 32 + (lane >> 4) * 8 + j;
            int g = kg >> 7, ic = kg & 127;
            aw[idx] = f2bf(w[(m * 128 + ic) * 9 + g]);
        }
        return;
    }
    __shared__ unsigned short tile[128 * 57];
    int b = blk / NH, y = blk % NH;
    const float* xb = x + (size_t)b * (NC * NPOS) + y * NW;
#pragma unroll
    for (int p = 0; p < 7; ++p) {
        int idx = p * 256 + tid;            // 1792 float4 = 7168 floats
        int c = idx / 14, i = idx - c * 14;
        float4 v = *(const float4*)(xb + c * NPOS + i * 4);
        unsigned short* tp = &tile[c * 57 + i * 4];
        tp[0] = f2bf(v.x); tp[1] = f2bf(v.y); tp[2] = f2bf(v.z); tp[3] = f2bf(v.w);
    }
    __syncthreads();
    unsigned short* xrow = xt + ((size_t)(b * HP + y + 1) * WP + 1) * NC;
#pragma unroll
    for (int p = 0; p < 4; ++p) {
        int idx = p * 256 + tid;            // 896 = 56 x-pos * 16 chunks
        if (idx < 896) {
            int xp = idx >> 4, cgi = idx & 15;
            s16x8 v8;
#pragma unroll
            for (int j = 0; j < 8; ++j)
                v8[j] = (short)tile[(cgi * 8 + j) * 57 + xp];
            int key = ((y + 1) * WP + (xp + 1)) & 15;
            *(s16x8*)(xrow + xp * NC + ((cgi ^ key) * 8)) = v8;
        }
    }
    if (tid < 128) {
        xt[((size_t)(b * HP + y + 1) * WP + 0) * NC + tid] = 0;
        xt[((size_t)(b * HP + y + 1) * WP + 57) * NC + tid] = 0;
    }
    if (y == 0) {
        unsigned short* r0 = xt + (size_t)(b * HP + 0) * WP * NC;
        for (int i = tid; i < WP * NC; i += 256) r0[i] = 0;
    }
    if (y == 55) {
        unsigned short* r57 = xt + (size_t)(b * HP + 57) * WP * NC;
        for (int i = tid; i < WP * NC; i += 256) r57[i] = 0;
    }
}

// ---- main v6: barrier-free K-loop via one-shot input slab ----
// All 9 taps of the 3x3 conv for one N=112 tile (2 image rows) read the same
// (2+2)-padded-row x 58-col x 128-ch input slab (59KB). Stage it into LDS
// ONCE (linear gld16 copy, 16-row-aligned base), then run the whole K=1152
// loop with ZERO barriers and ZERO restaging: tap st reads the slab at row
// offset toff = (dy)*58+dx. B-chunk XOR swizzle keyed on absolute padded row
// (mod 16) keeps ds_read_b128 ~conflict-free. A: beat-granular reg ping-pong
// from L2-resident aw (proven). 2 waves/SIMD free-run; no vmcnt(0) anywhere
// in the loop. Register footprint ~= 132us baseline (gB[4] freed, R0[7] added).
__global__ void __launch_bounds__(512, 2) k_main(
    const unsigned short* __restrict__ xt, const unsigned short* __restrict__ aw,
    const float* __restrict__ cwr, const float* __restrict__ cwc,
    const float* __restrict__ brow, const float* __restrict__ bcol,
    const float* __restrict__ bch, float* __restrict__ out) {
    __shared__ __align__(16) unsigned char slab[248 * 256];   // 63,488 B

    const int tid = threadIdx.x;
    const int lane = tid & 63;
    const int wv = tid >> 6;
    const int l15 = lane & 15, quad = lane >> 4;
    const int ph = (wv & 1) * 2;            // per-parity sub-slice rotation
    const int blk = blockIdx.x;
    const int b = blk / 28;
    const int pt = blk - b * 28;
    const int tile0 = pt * 112;
    const int sbase = (pt * 116) & ~15;     // 16-aligned slab start row

    const unsigned char* src = (const unsigned char*)xt
                             + ((size_t)b * (HP * WP) + sbase) * 256;
    const unsigned char* gA = (const unsigned char*)aw + wv * 1024 + lane * 16;

    // per-lane slab row index (center tap) for each n-subtile
    int R0[7];
#pragma unroll
    for (int t = 0; t < 7; ++t) {
        int pos = tile0 + t * 16 + l15;
        int yy = pos / 56, xx = pos - yy * 56;
        R0[t] = (yy + 1) * WP + (xx + 1) - sbase;
    }

    // stage slab: 3968 x 16B linear copy (248 rows; tail overreads <=16 rows
    // into the adjacent ws region - allocated, values unused)
#pragma unroll
    for (int i = 0; i < 7; ++i)
        gld16(src + (size_t)(i * 512 + tid) * 16,
              (unsigned char*)slab + (i * 512 + wv * 64) * 16);
    if (wv < 6)
        gld16(src + (size_t)(7 * 512 + tid) * 16,
              (unsigned char*)slab + (7 * 512 + wv * 64) * 16);

    s16x8 Areg[2][4];          // [pingpong][rank]
    f32x4 acc[4][7] = {};      // [rank][ntile]

    auto aload = [&](int s32, int pp) {
#pragma unroll
        for (int r = 0; r < 4; ++r)
            Areg[pp][r] = *(const s16x8*)(gA + s32 * 32768 + r * 8192);
    };

    aload(ph, 0);              // first slice in this wave's rotated sequence
    __syncthreads();           // slab ready (compiler drains gld16 here, once)

    for (int st = 0; st < 9; ++st) {
        int dy = (st * 11) >> 5;                 // 0,0,0,1,1,1,2,2,2
        int toff = (dy - 1) * WP + (st - dy * 3 - 1);
#pragma unroll
        for (int j = 0; j < 4; ++j) {
            const int kkw = (j + ph) & 3;        // this wave's sub-slice this beat
            if (!(st == 8 && j == 3)) {
                int nslice = (j < 3) ? st * 4 + (((j + 1) + ph) & 3)
                                     : (st + 1) * 4 + ph;
                aload(nslice, (j + 1) & 1);
            }
            s16x8 bf[7];
#pragma unroll
            for (int t = 0; t < 7; ++t) {
                int Rt = R0[t] + toff;
                bf[t] = *(const s16x8*)((const unsigned char*)slab
                          + (Rt << 8) + (((kkw * 4 + quad) ^ (Rt & 15)) << 4));
            }
#pragma unroll
            for (int r = 0; r < 4; ++r)
#pragma unroll
                for (int t = 0; t < 7; ++t)
                    acc[r][t] = __builtin_amdgcn_mfma_f32_16x16x32_bf16(
                        Areg[j & 1][r], bf[t], acc[r][t], 0, 0, 0);
        }
    }

    // epilogue: inline softmax over rank + combine + biases, fp32 store
#pragma unroll
    for (int t = 0; t < 7; ++t) {
        int pos = tile0 + t * 16 + l15;
        int yy = pos / 56, xx = pos - yy * 56;
        float v0 = cwr[yy]       + cwc[xx];
        float v1 = cwr[56 + yy]  + cwc[56 + xx];
        float v2 = cwr[112 + yy] + cwc[112 + xx];
        float v3 = cwr[168 + yy] + cwc[168 + xx];
        float mx = fmaxf(fmaxf(v0, v1), fmaxf(v2, v3));
        float e0 = __expf(v0 - mx), e1 = __expf(v1 - mx);
        float e2 = __expf(v2 - mx), e3 = __expf(v3 - mx);
        float inv = 1.0f / (e0 + e1 + e2 + e3);
        float c0 = e0 * inv, c1 = e1 * inv, c2 = e2 * inv, c3 = e3 * inv;
        float rb = brow[yy] + bcol[xx];
#pragma unroll
        for (int r = 0; r < 4; ++r) {
            int ch = wv * 16 + quad * 4 + r;
            float v = acc[0][t][r] * c0 + acc[1][t][r] * c1
                    + acc[2][t][r] * c2 + acc[3][t][r] * c3;
            out[((size_t)b * NC + ch) * NPOS + pos] = v + bch[ch] + rb;
        }
    }
}

extern "C" void kernel_launch(void* const* d_in, const int* in_sizes, int n_in,
                              void* d_out, int out_size, void* d_ws, size_t ws_size,
                              hipStream_t stream) {
    const float* x    = (const float*)d_in[0];
    const float* w    = (const float*)d_in[1];
    const float* cwr  = (const float*)d_in[2];
    const float* cwc  = (const float*)d_in[3];
    const float* brow = (const float*)d_in[4];
    const float* bcol = (const float*)d_in[5];
    const float* bch  = (const float*)d_in[6];
    float* out = (float*)d_out;

    unsigned char* ws = (unsigned char*)d_ws;
    unsigned short* xt = (unsigned short*)ws;
    unsigned short* aw = (unsigned short*)(ws + AW_OFF);

    k_pro<<<4096, 256, 0, stream>>>(x, w, xt, aw);   // xpose + wconv fused
    k_main<<<NB * 28, 512, 0, stream>>>(xt, aw, cwr, cwc, brow, bcol, bch, out);
}

// Round 7
// 227.151 us; speedup vs baseline: 1.0908x; 1.0026x over previous
//
#include <hip/hip_runtime.h>

#define NB 32
#define NC 128
#define NH 56
#define NW 56
#define HP 58
#define WP 58
#define KK 1152
#define NPOS 3136                         // 56*56
#define XT_BYTES (NB * HP * WP * NC * 2)  // 27,557,888
#define AW_OFF XT_BYTES

typedef __attribute__((ext_vector_type(8))) short s16x8;
typedef __attribute__((ext_vector_type(4))) float f32x4;
typedef unsigned int u32;

__device__ __forceinline__ unsigned short f2bf(float f) {
    union { float f; unsigned int u; } v; v.f = f;
    unsigned int u = v.u + 0x7fffu + ((v.u >> 16) & 1u);
    return (unsigned short)(u >> 16);
}

__device__ __forceinline__ void gld16(const void* g, void* l) {
    __builtin_amdgcn_global_load_lds(
        (const __attribute__((address_space(1))) u32*)g,
        (__attribute__((address_space(3))) u32*)l, 16, 0, 0);
}

// ---- fused prologue (v1 + CENTER-POSITION-keyed chunk swizzle) ----
// xt row (Y,X) stores chunk c at phys c ^ key, key = ((Y-1)*56+(X-1)) & 15
// (= center position p & 15 for interior rows). A consumer reading tap
// (dy,dx) at position p needs key (p + dy*56+dx) & 15 — affine in p, so any
// 16 consecutive positions give bijective keys even across image-row
// crossings -> conflict-free ds_read_b128 for ALL taps (v6's row-keyed
// variant broke at row crossings: 3.1M conflicts). Pad rows are zero, so
// their (vacuous) permutation needs no special handling.
__global__ void k_pro(const float* __restrict__ x, const float* __restrict__ w,
                      unsigned short* __restrict__ xt, unsigned short* __restrict__ aw) {
    int blk = blockIdx.x;
    int tid = threadIdx.x;
    if (blk >= 1792) {
        int idx = (blk - 1792) * 256 + tid;   // 589824 total
        if (idx < 512 * KK) {
            int j = idx & 7, lane = (idx >> 3) & 63, mt = (idx >> 9) & 31, s = idx >> 14;
            int m = mt * 16 + (lane & 15);
            int kg = s * 32 + (lane >> 4) * 8 + j;
            int g = kg >> 7, ic = kg & 127;
            aw[idx] = f2bf(w[(m * 128 + ic) * 9 + g]);
        }
        return;
    }
    __shared__ unsigned short tile[128 * 57];
    int b = blk / NH, y = blk % NH;
    const float* xb = x + (size_t)b * (NC * NPOS) + y * NW;
#pragma unroll
    for (int p = 0; p < 7; ++p) {
        int idx = p * 256 + tid;            // 1792 float4 = 7168 floats
        int c = idx / 14, i = idx - c * 14;
        float4 v = *(const float4*)(xb + c * NPOS + i * 4);
        unsigned short* tp = &tile[c * 57 + i * 4];
        tp[0] = f2bf(v.x); tp[1] = f2bf(v.y); tp[2] = f2bf(v.z); tp[3] = f2bf(v.w);
    }
    __syncthreads();
    unsigned short* xrow = xt + ((size_t)(b * HP + y + 1) * WP + 1) * NC;
#pragma unroll
    for (int p = 0; p < 4; ++p) {
        int idx = p * 256 + tid;            // 896 = 56 x-pos * 16 chunks
        if (idx < 896) {
            int xp = idx >> 4, cgi = idx & 15;
            s16x8 v8;
#pragma unroll
            for (int j = 0; j < 8; ++j)
                v8[j] = (short)tile[(cgi * 8 + j) * 57 + xp];
            int key = (y * 56 + xp) & 15;   // center position mod 16
            *(s16x8*)(xrow + xp * NC + ((cgi ^ key) * 8)) = v8;
        }
    }
    if (tid < 128) {
        xt[((size_t)(b * HP + y + 1) * WP + 0) * NC + tid] = 0;
        xt[((size_t)(b * HP + y + 1) * WP + 57) * NC + tid] = 0;
    }
    if (y == 0) {
        unsigned short* r0 = xt + (size_t)(b * HP + 0) * WP * NC;
        for (int i = tid; i < WP * NC; i += 256) r0[i] = 0;
    }
    if (y == 55) {
        unsigned short* r57 = xt + (size_t)(b * HP + 57) * WP * NC;
        for (int i = tid; i < WP * NC; i += 256) r57[i] = 0;
    }
}

// ---- main v7: barrier-free slab loop x 4-wave blocks (2 blocks/CU) ----
// v6's slab loop (no barriers, no restaging in K) + v3's M-half split so the
// block is 256 threads: two independent blocks co-reside per CU (proven by
// v3's occupancy 29.5%), giving 4 free-running waves/SIMD to stack MFMA
// bursts into each other's ds_read/L2 latency gaps. Center-position-keyed
// swizzle (see k_pro) makes all slab reads conflict-free and t-uniform
// (one chunk offset per beat -> less VALU).
__global__ void __launch_bounds__(256, 2) k_main(
    const unsigned short* __restrict__ xt, const unsigned short* __restrict__ aw,
    const float* __restrict__ cwr, const float* __restrict__ cwc,
    const float* __restrict__ brow, const float* __restrict__ bcol,
    const float* __restrict__ bch, float* __restrict__ out) {
    __shared__ __align__(16) unsigned char slab[248 * 256];   // 63,488 B

    const int tid = threadIdx.x;
    const int lane = tid & 63;
    const int wv = tid >> 6;                // 0..3
    const int l15 = lane & 15, quad = lane >> 4;
    const int ph = (wv & 1) * 2;            // per-parity sub-slice rotation
    const int blk = blockIdx.x;
    const int b = blk / 56;
    const int rem = blk - b * 56;
    const int pt = rem >> 1;                // position tile [0,28)
    const int h = rem & 1;                  // channel half
    const int tile0 = pt * 112;
    const int sbase = (pt * 116) & ~15;     // 16-aligned slab start row

    const unsigned char* src = (const unsigned char*)xt
                             + ((size_t)b * (HP * WP) + sbase) * 256;
    // A rows: m = r*128 + h*64 + wv*16 + l15  ->  mt = 8r + 4h + wv
    const unsigned char* gA = (const unsigned char*)aw + (h * 4 + wv) * 1024 + lane * 16;

    // per-lane slab row index (center tap) for each n-subtile
    int R0[7];
#pragma unroll
    for (int t = 0; t < 7; ++t) {
        int pos = tile0 + t * 16 + l15;
        int yy = pos / 56, xx = pos - yy * 56;
        R0[t] = (yy + 1) * WP + (xx + 1) - sbase;
    }

    // stage slab: 3968 x 16B linear copy by 4 waves (15 full rounds + 128 tail;
    // tail overreads <=16 rows into adjacent ws region - allocated, unused)
#pragma unroll
    for (int i = 0; i < 15; ++i)
        gld16(src + (size_t)(i * 256 + tid) * 16,
              (unsigned char*)slab + (i * 256 + wv * 64) * 16);
    if (tid < 128)
        gld16(src + (size_t)(3840 + tid) * 16,
              (unsigned char*)slab + (3840 + wv * 64) * 16);

    s16x8 Areg[2][4];          // [pingpong][rank]
    f32x4 acc[4][7] = {};      // [rank][ntile]

    auto aload = [&](int s32, int pp) {
#pragma unroll
        for (int r = 0; r < 4; ++r)
            Areg[pp][r] = *(const s16x8*)(gA + s32 * 32768 + r * 8192);
    };

    aload(ph, 0);              // first slice in this wave's rotated sequence
    __syncthreads();           // slab ready (single gld16 drain, outside loop)

    for (int st = 0; st < 9; ++st) {
        int dy = (st * 11) >> 5;                 // 0,0,0,1,1,1,2,2,2
        int dxi = st - dy * 3;                   // 0,1,2
        int toff = (dy - 1) * WP + (dxi - 1);    // slab row offset
        int key = (l15 + (dy - 1) * 56 + (dxi - 1) + 64) & 15;  // position key
#pragma unroll
        for (int j = 0; j < 4; ++j) {
            const int kkw = (j + ph) & 3;        // this wave's sub-slice this beat
            if (!(st == 8 && j == 3)) {
                int nslice = (j < 3) ? st * 4 + (((j + 1) + ph) & 3)
                                     : (st + 1) * 4 + ph;
                aload(nslice, (j + 1) & 1);
            }
            const int coff = ((kkw * 4 + quad) ^ key) << 4;   // t-uniform
            s16x8 bf[7];
#pragma unroll
            for (int t = 0; t < 7; ++t)
                bf[t] = *(const s16x8*)((const unsigned char*)slab
                          + ((R0[t] + toff) << 8) + coff);
#pragma unroll
            for (int r = 0; r < 4; ++r)
#pragma unroll
                for (int t = 0; t < 7; ++t)
                    acc[r][t] = __builtin_amdgcn_mfma_f32_16x16x32_bf16(
                        Areg[j & 1][r], bf[t], acc[r][t], 0, 0, 0);
        }
    }

    // epilogue: inline softmax over rank + combine + biases, fp32 store
#pragma unroll
    for (int t = 0; t < 7; ++t) {
        int pos = tile0 + t * 16 + l15;
        int yy = pos / 56, xx = pos - yy * 56;
        float v0 = cwr[yy]       + cwc[xx];
        float v1 = cwr[56 + yy]  + cwc[56 + xx];
        float v2 = cwr[112 + yy] + cwc[112 + xx];
        float v3 = cwr[168 + yy] + cwc[168 + xx];
        float mx = fmaxf(fmaxf(v0, v1), fmaxf(v2, v3));
        float e0 = __expf(v0 - mx), e1 = __expf(v1 - mx);
        float e2 = __expf(v2 - mx), e3 = __expf(v3 - mx);
        float inv = 1.0f / (e0 + e1 + e2 + e3);
        float c0 = e0 * inv, c1 = e1 * inv, c2 = e2 * inv, c3 = e3 * inv;
        float rb = brow[yy] + bcol[xx];
#pragma unroll
        for (int r = 0; r < 4; ++r) {
            int ch = h * 64 + wv * 16 + quad * 4 + r;
            float v = acc[0][t][r] * c0 + acc[1][t][r] * c1
                    + acc[2][t][r] * c2 + acc[3][t][r] * c3;
            out[((size_t)b * NC + ch) * NPOS + pos] = v + bch[ch] + rb;
        }
    }
}

extern "C" void kernel_launch(void* const* d_in, const int* in_sizes, int n_in,
                              void* d_out, int out_size, void* d_ws, size_t ws_size,
                              hipStream_t stream) {
    const float* x    = (const float*)d_in[0];
    const float* w    = (const float*)d_in[1];
    const float* cwr  = (const float*)d_in[2];
    const float* cwc  = (const float*)d_in[3];
    const float* brow = (const float*)d_in[4];
    const float* bcol = (const float*)d_in[5];
    const float* bch  = (const float*)d_in[6];
    float* out = (float*)d_out;

    unsigned char* ws = (unsigned char*)d_ws;
    unsigned short* xt = (unsigned short*)ws;
    unsigned short* aw = (unsigned short*)(ws + AW_OFF);

    k_pro<<<4096, 256, 0, stream>>>(x, w, xt, aw);   // xpose + wconv fused
    k_main<<<NB * 56, 256, 0, stream>>>(xt, aw, cwr, cwc, brow, bcol, bch, out);
}